// Round 13
// baseline (244.894 us; speedup 1.0000x reference)
//
#include <hip/hip_runtime.h>
#include <stdint.h>

#define DD 768
#define HN 8
#define LL 4096
#define BB 32
#define ROWS 64                 // rows per 1-wave block
#define NBLK (BB * LL / ROWS)   // 2048 blocks = 8/CU x 256 CU
#define NP (ROWS / 2)           // 32 row-pairs
#define PSTR 772                // per-(block,head) partial: S[768], se at [768]

#define GLOBAL_AS __attribute__((address_space(1)))
#define LDS_AS    __attribute__((address_space(3)))

typedef __attribute__((ext_vector_type(2))) float f2;

// element offset for f2 fragment k: matches float4 LDS-read layout exactly
#define F2OFF(k, lane) (((k) >> 1) * 256 + (lane) * 4 + ((k) & 1) * 2)

// ---- DPP wave64 sum: 6 rounds, VALU-only, 4-wide ILP ----
#define DPP_STEP(x, ctrl, rmask, bc)                                           \
  x += __int_as_float(__builtin_amdgcn_update_dpp(                             \
      0, __float_as_int(x), (ctrl), (rmask), 0xf, (bc)))

__device__ __forceinline__ void wave_sum4(float& a, float& b, float& c, float& d) {
  DPP_STEP(a, 0x111, 0xf, true);  DPP_STEP(b, 0x111, 0xf, true);
  DPP_STEP(c, 0x111, 0xf, true);  DPP_STEP(d, 0x111, 0xf, true);
  DPP_STEP(a, 0x112, 0xf, true);  DPP_STEP(b, 0x112, 0xf, true);
  DPP_STEP(c, 0x112, 0xf, true);  DPP_STEP(d, 0x112, 0xf, true);
  DPP_STEP(a, 0x114, 0xf, true);  DPP_STEP(b, 0x114, 0xf, true);
  DPP_STEP(c, 0x114, 0xf, true);  DPP_STEP(d, 0x114, 0xf, true);
  DPP_STEP(a, 0x118, 0xf, true);  DPP_STEP(b, 0x118, 0xf, true);
  DPP_STEP(c, 0x118, 0xf, true);  DPP_STEP(d, 0x118, 0xf, true);
  DPP_STEP(a, 0x142, 0xa, false); DPP_STEP(b, 0x142, 0xa, false);
  DPP_STEP(c, 0x142, 0xa, false); DPP_STEP(d, 0x142, 0xa, false);
  DPP_STEP(a, 0x143, 0xc, false); DPP_STEP(b, 0x143, 0xc, false);
  DPP_STEP(c, 0x143, 0xc, false); DPP_STEP(d, 0x143, 0xc, false);
  a = __int_as_float(__builtin_amdgcn_readlane(__float_as_int(a), 63));
  b = __int_as_float(__builtin_amdgcn_readlane(__float_as_int(b), 63));
  c = __int_as_float(__builtin_amdgcn_readlane(__float_as_int(c), 63));
  d = __int_as_float(__builtin_amdgcn_readlane(__float_as_int(d), 63));
}

// ---------------- kernel 0: RAW qk[h][d] = gamma1[d]*scale*sum_i q[h*96+i]*w[h*96+i][d]
__global__ __launch_bounds__(256) void k_qk(const float* __restrict__ wkv,
                                            const float* __restrict__ query,
                                            const float* __restrict__ gamma1,
                                            float* __restrict__ qkraw) {
  int h = blockIdx.x / 3;
  int d = (blockIdx.x % 3) * 256 + threadIdx.x;
  const float* wbase = wkv + (size_t)h * 96 * DD + d;
  const float* qb = query + h * 96;
  float acc = 0.f;
  #pragma unroll 8
  for (int i = 0; i < 96; ++i) acc = fmaf(qb[i], wbase[(size_t)i * DD], acc);
  qkraw[h * DD + d] = acc * 0.10206207261596577f * gamma1[d];
}

// ---- row helpers: packed f2 math; cl[k] element order == float4 layout ----
__device__ __forceinline__ void rowacc(const float4& c0, const float4& c1, const float4& c2,
                                       const f2 (&q2)[HN][6],
                                       float& s1o, float& s2o, float (&dt)[HN]) {
  f2 cl[6];
  cl[0].x = c0.x; cl[0].y = c0.y;  cl[1].x = c0.z; cl[1].y = c0.w;
  cl[2].x = c1.x; cl[2].y = c1.y;  cl[3].x = c1.z; cl[3].y = c1.w;
  cl[4].x = c2.x; cl[4].y = c2.y;  cl[5].x = c2.z; cl[5].y = c2.w;
  f2 s1 = {0.f, 0.f}, s2 = {0.f, 0.f};
  f2 d[HN];
  #pragma unroll
  for (int h = 0; h < HN; ++h) { d[h].x = 0.f; d[h].y = 0.f; }
  #pragma unroll
  for (int k = 0; k < 6; ++k) {
    s1 += cl[k];
    s2 = __builtin_elementwise_fma(cl[k], cl[k], s2);
    #pragma unroll
    for (int h = 0; h < HN; ++h)
      d[h] = __builtin_elementwise_fma(cl[k], q2[h][k], d[h]);
  }
  s1o = s1.x + s1.y;
  s2o = s2.x + s2.y;
  #pragma unroll
  for (int h = 0; h < HN; ++h) dt[h] = d[h].x + d[h].y;
}

__device__ __forceinline__ void rowtail(float s1, float s2, const float (&dt)[HN],
                                        const float4& c0, const float4& c1, const float4& c2,
                                        f2 (&S2)[HN][6], float (&se)[HN], float (&ch)[HN]) {
  f2 cl[6];
  cl[0].x = c0.x; cl[0].y = c0.y;  cl[1].x = c0.z; cl[1].y = c0.w;
  cl[2].x = c1.x; cl[2].y = c1.y;  cl[3].x = c1.z; cl[3].y = c1.w;
  cl[4].x = c2.x; cl[4].y = c2.y;  cl[5].x = c2.z; cl[5].y = c2.w;
  float mu   = s1 * (1.f / 768.f);
  float var  = fmaf(-mu, mu, s2 * (1.f / 768.f));
  float rstd = rsqrtf(var + 1e-5f);
  float sh   = -mu * rstd;
  float pe   = rstd * 1.44269504f;
  #pragma unroll
  for (int h = 0; h < HN; ++h) {
    float p = exp2f(dt[h] * pe);
    se[h] += p;
    ch[h] = fmaf(p, sh, ch[h]);
    float a = p * rstd;
    f2 av; av.x = a; av.y = a;
    #pragma unroll
    for (int k = 0; k < 6; ++k)
      S2[h][k] = __builtin_elementwise_fma(av, cl[k], S2[h][k]);
  }
}

// ---------------- kernel 1: 1-wave blocks, 8 heads/wave, pair-iteration ring, pk-f32
__global__ __launch_bounds__(64, 2) void k_main(
    const float* __restrict__ x, const float* __restrict__ qkraw,
    float* __restrict__ part) {
  const int lane = threadIdx.x;          // 0..63
  __shared__ float lds[3][2][DD];        // 3 pair-slots (18 KB)
  float* ring = &lds[0][0][0];

  // q fragments: f2 pairs in FLOAT4-COMPATIBLE layout (F2OFF); center per head
  f2 q2[HN][6];
  #pragma unroll
  for (int h = 0; h < HN; ++h)
    #pragma unroll
    for (int k = 0; k < 6; ++k)
      q2[h][k] = *reinterpret_cast<const f2*>(qkraw + h * DD + F2OFF(k, lane));
  asm volatile("s_waitcnt vmcnt(0)" ::: "memory");  // q landed; vmcnt = stages only
  {
    float m[HN];
    #pragma unroll
    for (int h = 0; h < HN; ++h) {
      f2 t = {0.f, 0.f};
      #pragma unroll
      for (int k = 0; k < 6; ++k) t += q2[h][k];
      m[h] = t.x + t.y;
    }
    wave_sum4(m[0], m[1], m[2], m[3]);
    wave_sum4(m[4], m[5], m[6], m[7]);
    #pragma unroll
    for (int h = 0; h < HN; ++h) {
      float mv = m[h] * (1.f / 768.f);
      f2 mv2; mv2.x = mv; mv2.y = mv;
      #pragma unroll
      for (int k = 0; k < 6; ++k) q2[h][k] -= mv2;
    }
  }

  f2 S2[HN][6];
  float se[HN], ch[HN];
  #pragma unroll
  for (int h = 0; h < HN; ++h) {
    se[h] = 0.f; ch[h] = 0.f;
    #pragma unroll
    for (int k = 0; k < 6; ++k) { S2[h][k].x = 0.f; S2[h][k].y = 0.f; }
  }

  const float* gbase = x + (size_t)blockIdx.x * ROWS * DD;

  // stage pair P into pair-slot SLOT: 6x 16B DMA (6 vmcnt events)
  #define STAGEP(P, SLOT)                                                      \
    {                                                                          \
      const float* gt = gbase + (size_t)(P) * (2 * DD);                        \
      float* db = ring + (SLOT) * (2 * DD);                                    \
      _Pragma("unroll")                                                        \
      for (int i = 0; i < 6; ++i)                                              \
        __builtin_amdgcn_global_load_lds(                                      \
            (const GLOBAL_AS uint32_t*)(gt + i * 256 + lane * 4),              \
            (LDS_AS uint32_t*)(db + i * 256), 16, 0, 0);                       \
    }

  // compute pair at SLOT: 6 ds_read_b128, two rows, batched DPP reductions
  #define COMPUTEP(SLOT)                                                       \
    {                                                                          \
      const float* ra = ring + (SLOT) * (2 * DD);                              \
      float4 a0 = *reinterpret_cast<const float4*>(ra + lane * 4);             \
      float4 a1 = *reinterpret_cast<const float4*>(ra + 256 + lane * 4);       \
      float4 a2 = *reinterpret_cast<const float4*>(ra + 512 + lane * 4);       \
      float4 b0 = *reinterpret_cast<const float4*>(ra + 768 + lane * 4);       \
      float4 b1 = *reinterpret_cast<const float4*>(ra + 1024 + lane * 4);      \
      float4 b2 = *reinterpret_cast<const float4*>(ra + 1280 + lane * 4);      \
      float s1a, s2a, s1b, s2b;                                                \
      float dta[HN], dtb[HN];                                                  \
      rowacc(a0, a1, a2, q2, s1a, s2a, dta);                                   \
      rowacc(b0, b1, b2, q2, s1b, s2b, dtb);                                   \
      wave_sum4(s1a, s2a, s1b, s2b);                                           \
      wave_sum4(dta[0], dta[1], dta[2], dta[3]);                               \
      wave_sum4(dta[4], dta[5], dta[6], dta[7]);                               \
      wave_sum4(dtb[0], dtb[1], dtb[2], dtb[3]);                               \
      wave_sum4(dtb[4], dtb[5], dtb[6], dtb[7]);                               \
      rowtail(s1a, s2a, dta, a0, a1, a2, S2, se, ch);                          \
      rowtail(s1b, s2b, dtb, b0, b1, b2, S2, se, ch);                          \
    }

  // prologue: 3 pairs in flight (18 loads) into slots 0,1,2
  STAGEP(0, 0) STAGEP(1, 1) STAGEP(2, 2)

  int slot = 0;
  #pragma unroll 1
  for (int p = 0; p <= NP - 3; ++p) {
    asm volatile("s_waitcnt vmcnt(12)" ::: "memory");  // pair p landed
    COMPUTEP(slot)
    if (p + 3 < NP) STAGEP(p + 3, slot)                // reuse pair p's slot
    slot = (slot == 2) ? 0 : slot + 1;
  }
  asm volatile("s_waitcnt vmcnt(6)" ::: "memory");
  COMPUTEP(slot)
  slot = (slot == 2) ? 0 : slot + 1;
  asm volatile("s_waitcnt vmcnt(0)" ::: "memory");
  COMPUTEP(slot)

  #undef COMPUTEP
  #undef STAGEP

  // epilogue: wave-private partial write — SAME absolute element positions as R11
  float* pb = part + (size_t)blockIdx.x * (HN * PSTR);
  #pragma unroll
  for (int h = 0; h < HN; ++h) {
    f2 ch2; ch2.x = ch[h]; ch2.y = ch[h];
    #pragma unroll
    for (int k = 0; k < 6; ++k) {
      f2 v = S2[h][k] + ch2;
      *reinterpret_cast<f2*>(pb + h * PSTR + F2OFF(k, lane)) = v;
    }
  }
  if (lane == 0) {
    #pragma unroll
    for (int h = 0; h < HN; ++h) pb[h * PSTR + 768] = se[h];
  }
}

// ---------------- kernel 2a: combine 64 chunk partials -> xbar[b][h][768]
__global__ __launch_bounds__(256) void k_red(const float* __restrict__ part,
                                             const float* __restrict__ gamma1,
                                             const float* __restrict__ beta1,
                                             float* __restrict__ xbar) {
  int b = blockIdx.x >> 3;
  int h = blockIdx.x & 7;
  int t = threadIdx.x;
  const int CPB = LL / ROWS;   // 64 chunks per batch
  const float* pb = part + ((size_t)b * CPB * HN + h) * PSTR;
  float se = 0.f, a0 = 0.f, a1 = 0.f, a2 = 0.f;
  #pragma unroll 4
  for (int i = 0; i < CPB; ++i) {
    const float* P = pb + (size_t)i * HN * PSTR;
    se += P[768];
    a0 += P[t];
    a1 += P[t + 256];
    a2 += P[t + 512];
  }
  float inv = 1.f / se;
  size_t ob = ((size_t)b * HN + h) * DD;
  xbar[ob + t]       = fmaf(gamma1[t],       a0 * inv, beta1[t]);
  xbar[ob + t + 256] = fmaf(gamma1[t + 256], a1 * inv, beta1[t + 256]);
  xbar[ob + t + 512] = fmaf(gamma1[t + 512], a2 * inv, beta1[t + 512]);
}

// ---------------- kernel 2b: V-projection (96 blocks: 32 b x 3 g-chunks)
__global__ __launch_bounds__(256) void k_proj(
    const float* __restrict__ xbar, const float* __restrict__ wkv,
    float* __restrict__ outp) {
  int b  = blockIdx.x / 3;
  int gc = blockIdx.x % 3;
  int t  = threadIdx.x;
  __shared__ float xb[HN * DD];
  #pragma unroll
  for (int k = 0; k < 24; ++k) xb[k * 256 + t] = xbar[(size_t)b * HN * DD + k * 256 + t];
  __syncthreads();

  int g = gc * 256 + t;
  int h = g / 96;
  const float4* wrow = reinterpret_cast<const float4*>(wkv + (size_t)(DD + g) * DD);
  const float* xh = xb + h * DD;
  float acc = 0.f;
  #pragma unroll 4
  for (int e = 0; e < 192; ++e) {
    float4 w = wrow[e];
    acc = fmaf(w.x, xh[e * 4 + 0], acc);
    acc = fmaf(w.y, xh[e * 4 + 1], acc);
    acc = fmaf(w.z, xh[e * 4 + 2], acc);
    acc = fmaf(w.w, xh[e * 4 + 3], acc);
  }
  outp[(size_t)b * DD + g] = acc;
}

// ---------------- kernel 2c: final LN over 768
__global__ __launch_bounds__(768) void k_ln2(
    const float* __restrict__ outp, const float* __restrict__ gamma2,
    const float* __restrict__ beta2, float* __restrict__ out) {
  int b = blockIdx.x;
  int t = threadIdx.x;
  __shared__ float rs1[12], rs2[12];
  __shared__ float smu, srstd;
  float o = outp[(size_t)b * DD + t];
  float v1 = o, v2 = o * o;
  #pragma unroll
  for (int off = 1; off < 64; off <<= 1) {
    v1 += __shfl_xor(v1, off, 64);
    v2 += __shfl_xor(v2, off, 64);
  }
  int wv = t >> 6, ln = t & 63;
  if (ln == 0) { rs1[wv] = v1; rs2[wv] = v2; }
  __syncthreads();
  if (t == 0) {
    float s1 = 0.f, s2 = 0.f;
    #pragma unroll
    for (int w = 0; w < 12; ++w) { s1 += rs1[w]; s2 += rs2[w]; }
    float mu = s1 * (1.f / 768.f);
    float var = fmaf(-mu, mu, s2 * (1.f / 768.f));
    smu = mu;
    srstd = rsqrtf(var + 1e-5f);
  }
  __syncthreads();
  out[(size_t)b * DD + t] = fmaf((o - smu) * srstd, gamma2[t], beta2[t]);
}

extern "C" void kernel_launch(void* const* d_in, const int* in_sizes, int n_in,
                              void* d_out, int out_size, void* d_ws, size_t ws_size,
                              hipStream_t stream) {
  const float* x     = (const float*)d_in[0];
  const float* wkv   = (const float*)d_in[1];
  const float* query = (const float*)d_in[2];
  const float* g1    = (const float*)d_in[3];
  const float* b1    = (const float*)d_in[4];
  const float* g2    = (const float*)d_in[5];
  const float* b2    = (const float*)d_in[6];
  float* out = (float*)d_out;
  float* ws  = (float*)d_ws;

  float* qkraw = ws;                                   // 6144 floats (pad 8192)
  float* part  = ws + 8192;                            // NBLK*HN*PSTR (~50.6 MB)
  float* xbar  = part + (size_t)NBLK * HN * PSTR;      // BB*HN*DD
  float* outp  = xbar + (size_t)BB * HN * DD;          // BB*DD

  k_qk  <<<24,      256, 0, stream>>>(wkv, query, g1, qkraw);
  k_main<<<NBLK,    64,  0, stream>>>(x, qkraw, part);
  k_red <<<BB * HN, 256, 0, stream>>>(part, g1, b1, xbar);
  k_proj<<<BB * 3,  256, 0, stream>>>(xbar, wkv, outp);
  k_ln2 <<<BB,      768, 0, stream>>>(outp, g2, b2, out);
}